// Round 4
// baseline (56.288 us; speedup 1.0000x reference)
//
#include <hip/hip_runtime.h>

// UnPooling3D: input (4,32,32,32,64) f32 -> output (4,64,64,64,64) f32.
// out[b, 2d, 2h, 2w, c] = in[b, d, h, w, c]; else zero. Memory-bound.
//
// Bit-exact specialization (i = blk*4096 + k*256 + tid, no carries):
//   c4 = tid&15, wo-parity = tid bit4, ho-parity = k bit2, dd-parity = blk bit4.
// => odd-d blocks (half the grid) are PURE FILL: branch-free 16x nt-store.
// => even-d blocks: loads exist only for k&4==0 steps and tid&16==0 lanes,
//    both compile-time/wave-uniform — no per-element compare chains.

#define UNROLL 16

typedef float f4 __attribute__((ext_vector_type(4)));

__global__ __launch_bounds__(256) void unpool3d_kernel(
    const f4* __restrict__ in, f4* __restrict__ out) {
    const int blk  = blockIdx.x;
    const int base = blk * (256 * UNROLL) + threadIdx.x;
    const f4 z = {0.f, 0.f, 0.f, 0.f};

    if ((blk >> 4) & 1) {               // dd odd: whole block is zeros — pure fill
#pragma unroll
        for (int k = 0; k < UNROLL; ++k)
            __builtin_nontemporal_store(z, &out[base + k * 256]);
        return;
    }

    f4 v[UNROLL];
#pragma unroll
    for (int k = 0; k < UNROLL; ++k) {
        v[k] = z;
        if ((k & 4) == 0) {             // ho even (compile-time per unrolled k)
            if ((threadIdx.x & 16) == 0) {   // wo even (wave-uniform half-mask)
                const int i     = base + k * 256;
                const int c4    = i & 15;
                const int voxel = i >> 4;
                const int wo = voxel & 63;
                const int ho = (voxel >> 6) & 63;
                const int dd = (voxel >> 12) & 63;
                const int b  = voxel >> 18;
                const int in_voxel =
                    ((b * 32 + (dd >> 1)) * 32 + (ho >> 1)) * 32 + (wo >> 1);
                v[k] = in[in_voxel * 16 + c4];
            }
        }
    }
#pragma unroll
    for (int k = 0; k < UNROLL; ++k)
        __builtin_nontemporal_store(v[k], &out[base + k * 256]);
}

extern "C" void kernel_launch(void* const* d_in, const int* in_sizes, int n_in,
                              void* d_out, int out_size, void* d_ws, size_t ws_size,
                              hipStream_t stream) {
    const f4* in = (const f4*)d_in[0];
    f4* out = (f4*)d_out;
    const int n4 = out_size / 4;                 // 16,777,216 float4s
    const int grid = n4 / (256 * UNROLL);        // 4096 blocks, exact (no tail)
    unpool3d_kernel<<<grid, 256, 0, stream>>>(in, out);
}

// Round 6
// 55.584 us; speedup vs baseline: 1.0127x; 1.0127x over previous
//
#include <hip/hip_runtime.h>

// UnPooling3D: input (4,32,32,32,64) f32 -> output (4,64,64,64,64) f32.
// out[b, 2d, 2h, 2w, c] = in[b, d, h, w, c]; else zero. Memory-bound.
//
// TWO SEQUENTIAL PHASES for DRAM stream homogeneity:
//   A) pure-write zero fill of the 7/8 complement (235 MB, fill-rate phase)
//   B) streaming copy of input to the strided data positions (67 MB copy phase)
// Data f4 index predicate: i is data iff bits {4 (w-parity), 10 (h-parity),
// 16 (d-parity)} are all zero: (i & 0x10410) == 0.
//
// Round-4 bug fixed: d+b field mask is 0x1FC000 (bits 14-20), NOT 0x1F4000
// (that dropped d bit1 -> wrong depth for d in {2,3,6,7,...}).

#define UNROLL 8

typedef float f4 __attribute__((ext_vector_type(4)));

// Phase A: write zeros everywhere EXCEPT data positions. Pure-write stream.
__global__ __launch_bounds__(256) void unpool3d_zero_kernel(
    f4* __restrict__ out) {
    const int base = blockIdx.x * (256 * UNROLL) + threadIdx.x;
    const f4 z = {0.f, 0.f, 0.f, 0.f};
#pragma unroll
    for (int k = 0; k < UNROLL; ++k) {
        const int i = base + k * 256;
        if ((i & 0x10410) != 0)
            __builtin_nontemporal_store(z, &out[i]);
    }
}

// Phase B: stream the input (perfectly contiguous reads) into the data
// positions. Out index is a bit-scatter of the input f4 index g:
//   c4 = g[0:3] -> out[0:3]; w = g[4:8] -> out[5:9]; h = g[9:13] -> out[11:15];
//   d = g[14:18] -> out[17:21]; b = g[19:20] -> out[22:23].
__global__ __launch_bounds__(256) void unpool3d_copy_kernel(
    const f4* __restrict__ in, f4* __restrict__ out) {
    const int base = blockIdx.x * (256 * UNROLL) + threadIdx.x;
    f4 v[UNROLL];
    int oidx[UNROLL];
#pragma unroll
    for (int k = 0; k < UNROLL; ++k) {
        const int g = base + k * 256;
        v[k] = in[g];
        oidx[k] = (g & 0xF) | ((g & 0x1F0) << 1) | ((g & 0x3E00) << 2)
                | ((g & 0x1FC000) << 3);
    }
#pragma unroll
    for (int k = 0; k < UNROLL; ++k)
        __builtin_nontemporal_store(v[k], &out[oidx[k]]);
}

extern "C" void kernel_launch(void* const* d_in, const int* in_sizes, int n_in,
                              void* d_out, int out_size, void* d_ws, size_t ws_size,
                              hipStream_t stream) {
    const f4* in = (const f4*)d_in[0];
    f4* out = (f4*)d_out;
    const int n4_out = out_size / 4;                     // 16,777,216 f4
    const int n4_in  = in_sizes[0] / 4;                  //  2,097,152 f4
    const int gridA = n4_out / (256 * UNROLL);           // 8192 blocks, exact
    const int gridB = n4_in  / (256 * UNROLL);           // 1024 blocks, exact
    unpool3d_zero_kernel<<<gridA, 256, 0, stream>>>(out);
    unpool3d_copy_kernel<<<gridB, 256, 0, stream>>>(in, out);
}

// Round 7
// 52.348 us; speedup vs baseline: 1.0753x; 1.0618x over previous
//
#include <hip/hip_runtime.h>

// UnPooling3D: input (4,32,32,32,64) f32 -> output (4,64,64,64,64) f32.
// out[b, 2d, 2h, 2w, c] = in[b, d, h, w, c]; else zero. Memory-bound.
//
// REVERT to round-2 structure (best measured: 52.2 us, 5.8 TB/s mixed).
// Single homogeneous pass over the output; 8x-unrolled batched loads (MLP)
// + non-temporal float4 stores. Tested-and-rejected alternatives:
//   - concurrent fill/data block specialization (r3): 56.3 us
//   - sequential fill-phase + copy-phase (r5): 55.6 us (holey fill stream +
//     double page-activation on data lines + 2nd launch ramp)

#define UNROLL 8

typedef float f4 __attribute__((ext_vector_type(4)));

__global__ __launch_bounds__(256) void unpool3d_kernel(
    const f4* __restrict__ in, f4* __restrict__ out) {
    const int base = blockIdx.x * (256 * UNROLL) + threadIdx.x;
    f4 v[UNROLL];
#pragma unroll
    for (int k = 0; k < UNROLL; ++k) {
        const int i = base + k * 256;
        const int c4    = i & 15;        // float4 index within 64-channel vector
        const int voxel = i >> 4;        // flat (b, d, h, w) over 64^3 spatial
        const int wo = voxel & 63;
        const int ho = (voxel >> 6) & 63;
        const int dd = (voxel >> 12) & 63;
        const int b  = voxel >> 18;
        v[k] = (f4){0.f, 0.f, 0.f, 0.f};
        if (((wo | ho | dd) & 1) == 0) {
            const int in_voxel = ((b * 32 + (dd >> 1)) * 32 + (ho >> 1)) * 32 + (wo >> 1);
            v[k] = in[in_voxel * 16 + c4];
        }
    }
#pragma unroll
    for (int k = 0; k < UNROLL; ++k)
        __builtin_nontemporal_store(v[k], &out[base + k * 256]);
}

extern "C" void kernel_launch(void* const* d_in, const int* in_sizes, int n_in,
                              void* d_out, int out_size, void* d_ws, size_t ws_size,
                              hipStream_t stream) {
    const f4* in = (const f4*)d_in[0];
    f4* out = (f4*)d_out;
    const int n4 = out_size / 4;                 // 16,777,216 float4s
    const int grid = n4 / (256 * UNROLL);        // 8192 blocks, exact (no tail)
    unpool3d_kernel<<<grid, 256, 0, stream>>>(in, out);
}